// Round 2
// baseline (202.352 us; speedup 1.0000x reference)
//
#include <hip/hip_runtime.h>
#include <stdint.h>

// ModulatedConv (StyleGAN2 up-conv): B=8, Cin=Cout=512, K=3, 32x32 -> 64x64.
// Inputs/outputs fp32 (reference dtype); internal GEMM in bf16 MFMA.
// Decomposition:
//   K1 dcoef[b][o]           (fp32, 16 KB ws)
//   K2 Wm[b][tap][o][i] bf16 (37.75 MB ws)  -- modulated+demodulated weights, GEMM-A layout
//   K3 XT[b][hw][i]     bf16 (8.39 MB ws)   -- x transposed to GEMM-B^T layout
//   K4 C[b*9+tap][o][hw]bf16 (75.5 MB ws)   -- 72 GEMMs 512x1024x512, MFMA 16x16x32 bf16
//   K5 out[b][o][64][64]fp32                -- parity scatter + separable 4x4 FIR, per-(b,o) in LDS

#define DI __device__ __forceinline__

typedef __bf16 bf16x8 __attribute__((ext_vector_type(8)));
typedef float f32x4 __attribute__((ext_vector_type(4)));

DI float bf2f(ushort u) { union { uint32_t i; float f; } v; v.i = ((uint32_t)u) << 16; return v.f; }
DI ushort f2bf(float f) {
  union { float f; uint32_t i; } v; v.f = f;
  uint32_t x = v.i;
  return (ushort)((x + 0x7FFFu + ((x >> 16) & 1u)) >> 16);  // RNE
}

#define GAIN (1.0f / 1536.0f)  // 1/sqrt(512*512*9)

// ---------------- K1: dcoef[b][o] = rsqrt(gain^2 * sum_i,k (w*(s+1))^2 + eps) ----------
__global__ __launch_bounds__(256) void k_dcoef(const float* __restrict__ w,
                                               const float* __restrict__ styles,
                                               float* __restrict__ dcoef) {
  const int bo = blockIdx.x;
  const int b = bo >> 9, o = bo & 511;
  const float* wrow = w + o * 4608;
  const float* srow = styles + b * 512;
  float sum = 0.f;
  for (int idx = threadIdx.x; idx < 4608; idx += 256) {
    float wv = wrow[idx];
    float sv = srow[idx / 9];
    float m = wv * (sv + 1.0f);
    sum += m * m;
  }
#pragma unroll
  for (int off = 32; off > 0; off >>= 1) sum += __shfl_down(sum, off, 64);
  __shared__ float red[4];
  if ((threadIdx.x & 63) == 0) red[threadIdx.x >> 6] = sum;
  __syncthreads();
  if (threadIdx.x == 0) {
    float t = red[0] + red[1] + red[2] + red[3];
    dcoef[bo] = rsqrtf(t * (GAIN * GAIN) + 1e-8f);
  }
}

// ---------------- K2: Wm[b][tap][o][i] = bf16(w*gain*(s+1)*dcoef) ----------------------
__global__ __launch_bounds__(256) void k_wmprep(const float* __restrict__ w,
                                                const float* __restrict__ styles,
                                                const float* __restrict__ dcoef,
                                                ushort* __restrict__ Wm) {
  const int gid = blockIdx.x * 256 + threadIdx.x;  // = o*512 + i
  const int o = gid >> 9, i = gid & 511;
  float wf[9];
#pragma unroll
  for (int t = 0; t < 9; t++) wf[t] = w[gid * 9 + t];
  for (int b = 0; b < 8; b++) {
    float s = styles[b * 512 + i];
    float d = dcoef[b * 512 + o];
    float scale = GAIN * (s + 1.0f) * d;
#pragma unroll
    for (int t = 0; t < 9; t++) Wm[(((b * 9 + t) * 512 + o) << 9) + i] = f2bf(wf[t] * scale);
  }
}

// ---------------- K3: XT[b][hw][i] = bf16(x[b][i][hw]) (LDS 32x32 tile transpose) ------
__global__ __launch_bounds__(256) void k_xt(const float* __restrict__ x,
                                            ushort* __restrict__ xt) {
  __shared__ float t[32][33];
  const int b = blockIdx.z, hw0 = blockIdx.x * 32, i0 = blockIdx.y * 32;
  const int tx = threadIdx.x & 31, ty = threadIdx.x >> 5;
  const float* xb = x + b * (512 * 1024);
#pragma unroll
  for (int r = 0; r < 4; r++) t[ty + r * 8][tx] = xb[(i0 + ty + r * 8) * 1024 + hw0 + tx];
  __syncthreads();
  ushort* xtb = xt + b * (1024 * 512);
#pragma unroll
  for (int r = 0; r < 4; r++) xtb[(hw0 + ty + r * 8) * 512 + i0 + tx] = f2bf(t[tx][ty + r * 8]);
}

// ---------------- K4: 72 x GEMM (M=512,N=1024,K=512), C = Wm @ X -----------------------
// A row-major [m=o][k=i], B^T row-major [n=hw][k=i]. 128x128 tile, BK=32, 4 waves.
__global__ __launch_bounds__(256) void k_gemm(const ushort* __restrict__ A,
                                              const ushort* __restrict__ Bt,
                                              ushort* __restrict__ C) {
  __shared__ __attribute__((aligned(16))) char smem[16384];  // A tile 8K | B tile 8K
  const int bx = blockIdx.x;
  const int g = bx >> 5;          // gemm id = b*9+tap
  const int tt = bx & 31;
  const int mt = tt >> 3, nt = tt & 7;
  const int b = g / 9;
  const ushort* Ag = A + g * (512 * 512);
  const ushort* Bg = Bt + b * (1024 * 512);
  ushort* Cg = C + g * (512 * 1024);
  const int tid = threadIdx.x;
  const int lane = tid & 63, wv = tid >> 6;
  const int m0 = mt * 128, n0 = nt * 128;
  const int wm2 = wv >> 1, wn2 = wv & 1;
  const int lq = lane >> 4, l15 = lane & 15;
  const char* abase = smem + (wm2 * 64 + l15) * 64 + lq * 16;
  const char* bbase = smem + 8192 + (wn2 * 64 + l15) * 64 + lq * 16;
  const int l4 = lane & 3, ld4 = lane >> 2;
  const int r0 = (0 * 4 + wv) * 16 + ld4;  // staging row for issue 0
  const int r1 = (1 * 4 + wv) * 16 + ld4;  // staging row for issue 1

  f32x4 zero = {0.f, 0.f, 0.f, 0.f};
  f32x4 acc[4][4];
#pragma unroll
  for (int mi = 0; mi < 4; mi++)
#pragma unroll
    for (int ni = 0; ni < 4; ni++) acc[mi][ni] = zero;

  for (int kc = 0; kc < 512; kc += 32) {
    const ushort* sA0 = Ag + (m0 + r0) * 512 + kc + l4 * 8;
    const ushort* sA1 = Ag + (m0 + r1) * 512 + kc + l4 * 8;
    const ushort* sB0 = Bg + (n0 + r0) * 512 + kc + l4 * 8;
    const ushort* sB1 = Bg + (n0 + r1) * 512 + kc + l4 * 8;
    __builtin_amdgcn_global_load_lds((const __attribute__((address_space(1))) void*)sA0,
                                     (__attribute__((address_space(3))) void*)(smem + (0 * 4 + wv) * 1024), 16, 0, 0);
    __builtin_amdgcn_global_load_lds((const __attribute__((address_space(1))) void*)sA1,
                                     (__attribute__((address_space(3))) void*)(smem + (1 * 4 + wv) * 1024), 16, 0, 0);
    __builtin_amdgcn_global_load_lds((const __attribute__((address_space(1))) void*)sB0,
                                     (__attribute__((address_space(3))) void*)(smem + 8192 + (0 * 4 + wv) * 1024), 16, 0, 0);
    __builtin_amdgcn_global_load_lds((const __attribute__((address_space(1))) void*)sB1,
                                     (__attribute__((address_space(3))) void*)(smem + 8192 + (1 * 4 + wv) * 1024), 16, 0, 0);
    __syncthreads();
    bf16x8 af[4], bfr[4];
#pragma unroll
    for (int mi = 0; mi < 4; mi++) af[mi] = *(const bf16x8*)(abase + mi * 1024);
#pragma unroll
    for (int ni = 0; ni < 4; ni++) bfr[ni] = *(const bf16x8*)(bbase + ni * 1024);
#pragma unroll
    for (int mi = 0; mi < 4; mi++)
#pragma unroll
      for (int ni = 0; ni < 4; ni++)
        acc[mi][ni] = __builtin_amdgcn_mfma_f32_16x16x32_bf16(af[mi], bfr[ni], acc[mi][ni], 0, 0, 0);
    __syncthreads();
  }
  // C/D layout (m89-verified): col = lane&15, row = quad*4 + reg
#pragma unroll
  for (int mi = 0; mi < 4; mi++) {
#pragma unroll
    for (int ni = 0; ni < 4; ni++) {
      const int row = m0 + wm2 * 64 + mi * 16 + lq * 4;
      const int col = n0 + wn2 * 64 + ni * 16 + l15;
      f32x4 v = acc[mi][ni];
#pragma unroll
      for (int r = 0; r < 4; r++) Cg[(row + r) * 1024 + col] = f2bf(v[r]);
    }
  }
}

// ---------------- K5: parity scatter + separable FIR, one (b,o) per block --------------
// Row terms (kh,s) with u+s-1-kh even, h=(u+s-1-kh)/2 in [0,32): exactly 6 per u.
// Stage1: V[kw][u][w] = sum_rowterms F[s]*C[kh][kw][h][w]
// Stage2: out[u][v] = (1/16) * sum_colterms F[t]*V[kw][u][w], w=(v+t-1-kw)/2
__global__ __launch_bounds__(256) void k_fir(const ushort* __restrict__ C,
                                             float* __restrict__ out) {
  const int bo = blockIdx.x;
  const int b = bo >> 9, o = bo & 511;
  __shared__ __attribute__((aligned(16))) ushort Ct[9 * 1024];
  __shared__ float V[3 * 64 * 32];
  __shared__ int rb[64][6];
  __shared__ float rc[64][6];
  __shared__ int cb[64][6];
  __shared__ float cc[64][6];
  const ushort* Cb = C + ((size_t)(b * 9) * 512 + o) * 1024;  // + tap*512*1024
  for (int c = threadIdx.x; c < 1152; c += 256) {
    const int tap = c >> 7, off = (c & 127) * 8;
    *(uint4*)&Ct[tap * 1024 + off] = *(const uint4*)&Cb[(size_t)tap * 524288 + off];
  }
  const float F[4] = {1.f, 3.f, 3.f, 1.f};
  if (threadIdx.x < 64) {
    const int u = threadIdx.x;
    int n = 0;
    for (int kh = 0; kh < 3; kh++)
      for (int s = 0; s < 4; s++) {
        int num = u + s - 1 - kh;
        if (num & 1) continue;
        int h = num >> 1;
        bool val = (h >= 0 && h < 32);
        rb[u][n] = val ? kh * 3072 + h * 32 : 0;
        rc[u][n] = val ? F[s] : 0.f;
        n++;
      }
  } else if (threadIdx.x < 128) {
    const int v = threadIdx.x - 64;
    int n = 0;
    for (int kw = 0; kw < 3; kw++)
      for (int t = 0; t < 4; t++) {
        int num = v + t - 1 - kw;
        if (num & 1) continue;
        int w = num >> 1;
        bool val = (w >= 0 && w < 32);
        cb[v][n] = val ? kw * 2048 + w : 0;
        cc[v][n] = val ? F[t] : 0.f;
        n++;
      }
  }
  __syncthreads();
#pragma unroll
  for (int j = 0; j < 6; j++) {
    const int gidx = threadIdx.x + j * 256;  // 0..1535 : (kw, u, w0/4)
    const int kw = gidx >> 9;
    const int rem = gidx & 511;
    const int u = rem >> 3;
    const int w0 = (rem & 7) * 4;
    float a0 = 0.f, a1 = 0.f, a2 = 0.f, a3 = 0.f;
#pragma unroll
    for (int n = 0; n < 6; n++) {
      const float cf = rc[u][n];
      const ushort* p = &Ct[rb[u][n] + kw * 1024 + w0];
      a0 += cf * bf2f(p[0]);
      a1 += cf * bf2f(p[1]);
      a2 += cf * bf2f(p[2]);
      a3 += cf * bf2f(p[3]);
    }
    float4* vp = (float4*)&V[kw * 2048 + u * 32 + w0];
    *vp = make_float4(a0, a1, a2, a3);
  }
  __syncthreads();
  const size_t ob = (size_t)bo * 4096;
#pragma unroll
  for (int j = 0; j < 16; j++) {
    const int px = threadIdx.x + j * 256;
    const int u = px >> 6, v = px & 63;
    float s = 0.f;
#pragma unroll
    for (int n = 0; n < 6; n++) s += cc[v][n] * V[cb[v][n] + u * 32];
    out[ob + px] = s * 0.0625f;
  }
}

extern "C" void kernel_launch(void* const* d_in, const int* in_sizes, int n_in,
                              void* d_out, int out_size, void* d_ws, size_t ws_size,
                              hipStream_t stream) {
  (void)in_sizes; (void)n_in; (void)out_size; (void)ws_size;
  const float* x = (const float*)d_in[0];       // [8,512,32,32] fp32
  const float* styles = (const float*)d_in[1];  // [8,512] fp32
  const float* w = (const float*)d_in[2];       // [512,512,3,3] fp32
  float* out = (float*)d_out;                   // [8,512,64,64] fp32
  char* ws = (char*)d_ws;
  float* dcoef = (float*)ws;                                        // 16384 B
  ushort* Wm = (ushort*)(ws + 16384);                               // 37748736 B
  ushort* XT = (ushort*)(ws + 16384 + 37748736);                    // 8388608 B
  ushort* C = (ushort*)(ws + 16384 + 37748736 + 8388608);           // 75497472 B

  k_dcoef<<<4096, 256, 0, stream>>>(w, styles, dcoef);
  k_wmprep<<<1024, 256, 0, stream>>>(w, styles, dcoef, Wm);
  k_xt<<<dim3(32, 16, 8), 256, 0, stream>>>(x, XT);
  k_gemm<<<2304, 256, 0, stream>>>(Wm, XT, C);
  k_fir<<<4096, 256, 0, stream>>>(C, out);
}

// Round 3
// 179.087 us; speedup vs baseline: 1.1299x; 1.1299x over previous
//
#include <hip/hip_runtime.h>
#include <stdint.h>

// ModulatedConv (StyleGAN2 up-conv): B=8, Cin=Cout=512, K=3, 32x32 -> 64x64, fp32 I/O.
// Pipeline:
//   K0 q[o][i]   = sum_t w^2            (1 MB ws)
//   K1 dcoef[b][o] = rsqrt(gain^2 * sum_i (s+1)^2 q + eps)   (16 KB ws)
//   K2 Wm[b][tap][o][i] bf16 (37.75 MB) -- modulated weights, GEMM-A layout
//   K3 XT[b][hw][i]     bf16 (8.39 MB)  -- x transposed to GEMM-B^T layout
//   K4 C[b*9+tap][o][hw]bf16 (75.5 MB)  -- 72 GEMMs 512x1024x512, MFMA 16x16x32 bf16,
//                                          XCD-swizzled (batch->XCD), LDS double-buffered
//   K5 out[b][o][64][64]fp32            -- parity scatter + separable 4x4 FIR per (b,o)

#define DI __device__ __forceinline__

typedef __bf16 bf16x8 __attribute__((ext_vector_type(8)));
typedef float f32x4 __attribute__((ext_vector_type(4)));

DI float bf2f(ushort u) { union { uint32_t i; float f; } v; v.i = ((uint32_t)u) << 16; return v.f; }
DI ushort f2bf(float f) {
  union { float f; uint32_t i; } v; v.f = f;
  uint32_t x = v.i;
  return (ushort)((x + 0x7FFFu + ((x >> 16) & 1u)) >> 16);  // RNE
}

#define GAIN (1.0f / 1536.0f)  // 1/sqrt(512*512*9)

// ---------------- K0: q[o*512+i] = sum_t w[o,i,t]^2 ------------------------------------
__global__ __launch_bounds__(256) void k_q(const float* __restrict__ w,
                                           float* __restrict__ q) {
  const int gid = blockIdx.x * 256 + threadIdx.x;  // o*512+i
  const float* p = w + gid * 9;
  float s = 0.f;
#pragma unroll
  for (int t = 0; t < 9; t++) s += p[t] * p[t];
  q[gid] = s;
}

// ---------------- K1: dcoef[b][o] = rsqrt(gain^2 * sum_i (s+1)^2 q[o][i] + eps) --------
__global__ __launch_bounds__(256) void k_dcoef(const float* __restrict__ q,
                                               const float* __restrict__ styles,
                                               float* __restrict__ dcoef) {
  const int bo = blockIdx.x * 4 + (threadIdx.x >> 6);  // 1024 blocks x 4 waves
  const int b = bo >> 9, o = bo & 511;
  const int lane = threadIdx.x & 63;
  float sum = 0.f;
#pragma unroll
  for (int j = 0; j < 8; j++) {
    const int i = lane + j * 64;
    float s = styles[b * 512 + i] + 1.0f;
    sum += s * s * q[o * 512 + i];
  }
#pragma unroll
  for (int off = 32; off > 0; off >>= 1) sum += __shfl_down(sum, off, 64);
  if (lane == 0) dcoef[bo] = rsqrtf(sum * (GAIN * GAIN) + 1e-8f);
}

// ---------------- K2: Wm[b][tap][o][i] = bf16(w*gain*(s+1)*dcoef) ----------------------
__global__ __launch_bounds__(256) void k_wmprep(const float* __restrict__ w,
                                                const float* __restrict__ styles,
                                                const float* __restrict__ dcoef,
                                                ushort* __restrict__ Wm) {
  const int gid = blockIdx.x * 256 + threadIdx.x;  // = o*512 + i
  const int o = gid >> 9, i = gid & 511;
  float wf[9];
#pragma unroll
  for (int t = 0; t < 9; t++) wf[t] = w[gid * 9 + t];
  for (int b = 0; b < 8; b++) {
    float s = styles[b * 512 + i];
    float d = dcoef[b * 512 + o];
    float scale = GAIN * (s + 1.0f) * d;
#pragma unroll
    for (int t = 0; t < 9; t++) Wm[(((b * 9 + t) * 512 + o) << 9) + i] = f2bf(wf[t] * scale);
  }
}

// ---------------- K3: XT[b][hw][i] = bf16(x[b][i][hw]) (LDS 32x32 tile transpose) ------
__global__ __launch_bounds__(256) void k_xt(const float* __restrict__ x,
                                            ushort* __restrict__ xt) {
  __shared__ float t[32][33];
  const int b = blockIdx.z, hw0 = blockIdx.x * 32, i0 = blockIdx.y * 32;
  const int tx = threadIdx.x & 31, ty = threadIdx.x >> 5;
  const float* xb = x + b * (512 * 1024);
#pragma unroll
  for (int r = 0; r < 4; r++) t[ty + r * 8][tx] = xb[(i0 + ty + r * 8) * 1024 + hw0 + tx];
  __syncthreads();
  ushort* xtb = xt + b * (1024 * 512);
#pragma unroll
  for (int r = 0; r < 4; r++) xtb[(hw0 + ty + r * 8) * 512 + i0 + tx] = f2bf(t[tx][ty + r * 8]);
}

// ---------------- K4: 72 x GEMM (M=512,N=1024,K=512), C = Wm @ X -----------------------
// A row-major [m=o][k=i], B^T row-major [n=hw][k=i]. 128x128 tile, BK=32, 4 waves.
// Block id: batch = id&7 (-> XCD via %8 round-robin), rem = id>>3, tap = rem>>5, t = rem&31.
// Per XCD: one batch, taps sequential -> B slab (1 MB) resident in L2, A slab read once.
// LDS double-buffered, ONE barrier per K-iter, prefetch issued right after barrier.
__global__ __launch_bounds__(256) void k_gemm(const ushort* __restrict__ A,
                                              const ushort* __restrict__ Bt,
                                              ushort* __restrict__ C) {
  __shared__ __attribute__((aligned(16))) char smem[32768];  // 2 x (A 8K | B 8K)
  const int id = blockIdx.x;
  const int batch = id & 7;
  const int rem = id >> 3;
  const int tap = rem >> 5;
  const int t = rem & 31;
  const int mt = t >> 3, nt = t & 7;
  const int g = batch * 9 + tap;
  const ushort* Ag = A + g * (512 * 512);
  const ushort* Bg = Bt + batch * (1024 * 512);
  ushort* Cg = C + g * (512 * 1024);
  const int tid = threadIdx.x;
  const int lane = tid & 63, wv = tid >> 6;
  const int m0 = mt * 128, n0 = nt * 128;
  const int wm2 = wv >> 1, wn2 = wv & 1;
  const int lq = lane >> 4, l15 = lane & 15;
  const int l4 = lane & 3, ld4 = lane >> 2;
  const int r0 = (0 * 4 + wv) * 16 + ld4;  // staging row for issue 0
  const int r1 = (1 * 4 + wv) * 16 + ld4;  // staging row for issue 1

  // global source base pointers (advance by kc each iter)
  const ushort* pA0 = Ag + (m0 + r0) * 512 + l4 * 8;
  const ushort* pA1 = Ag + (m0 + r1) * 512 + l4 * 8;
  const ushort* pB0 = Bg + (n0 + r0) * 512 + l4 * 8;
  const ushort* pB1 = Bg + (n0 + r1) * 512 + l4 * 8;
  char* dA0 = smem + (0 * 4 + wv) * 1024;
  char* dA1 = smem + (1 * 4 + wv) * 1024;
  char* dB0 = smem + 8192 + (0 * 4 + wv) * 1024;
  char* dB1 = smem + 8192 + (1 * 4 + wv) * 1024;

#define ISSUE(buf, kc)                                                                        \
  do {                                                                                        \
    __builtin_amdgcn_global_load_lds((const __attribute__((address_space(1))) void*)(pA0 + (kc)), \
                                     (__attribute__((address_space(3))) void*)(dA0 + (buf)*16384), 16, 0, 0); \
    __builtin_amdgcn_global_load_lds((const __attribute__((address_space(1))) void*)(pA1 + (kc)), \
                                     (__attribute__((address_space(3))) void*)(dA1 + (buf)*16384), 16, 0, 0); \
    __builtin_amdgcn_global_load_lds((const __attribute__((address_space(1))) void*)(pB0 + (kc)), \
                                     (__attribute__((address_space(3))) void*)(dB0 + (buf)*16384), 16, 0, 0); \
    __builtin_amdgcn_global_load_lds((const __attribute__((address_space(1))) void*)(pB1 + (kc)), \
                                     (__attribute__((address_space(3))) void*)(dB1 + (buf)*16384), 16, 0, 0); \
  } while (0)

  const char* abase = smem + (wm2 * 64 + l15) * 64 + lq * 16;
  const char* bbase = smem + 8192 + (wn2 * 64 + l15) * 64 + lq * 16;

  f32x4 zero = {0.f, 0.f, 0.f, 0.f};
  f32x4 acc[4][4];
#pragma unroll
  for (int mi = 0; mi < 4; mi++)
#pragma unroll
    for (int ni = 0; ni < 4; ni++) acc[mi][ni] = zero;

  ISSUE(0, 0);
  for (int it = 0; it < 16; ++it) {
    __syncthreads();  // drains cur-buf loads; guarantees prior reads of nxt buf finished
    const int cur = it & 1;
    if (it < 15) ISSUE(cur ^ 1, (it + 1) * 32);  // overlaps with ds_read + MFMA below
    const int bo = cur * 16384;
    bf16x8 af[4], bfr[4];
#pragma unroll
    for (int mi = 0; mi < 4; mi++) af[mi] = *(const bf16x8*)(abase + bo + mi * 1024);
#pragma unroll
    for (int ni = 0; ni < 4; ni++) bfr[ni] = *(const bf16x8*)(bbase + bo + ni * 1024);
#pragma unroll
    for (int mi = 0; mi < 4; mi++)
#pragma unroll
      for (int ni = 0; ni < 4; ni++)
        acc[mi][ni] = __builtin_amdgcn_mfma_f32_16x16x32_bf16(af[mi], bfr[ni], acc[mi][ni], 0, 0, 0);
  }
#undef ISSUE
  // C/D layout (m89-verified): col = lane&15, row = quad*4 + reg
#pragma unroll
  for (int mi = 0; mi < 4; mi++) {
#pragma unroll
    for (int ni = 0; ni < 4; ni++) {
      const int row = m0 + wm2 * 64 + mi * 16 + lq * 4;
      const int col = n0 + wn2 * 64 + ni * 16 + l15;
      f32x4 v = acc[mi][ni];
#pragma unroll
      for (int r = 0; r < 4; r++) Cg[(row + r) * 1024 + col] = f2bf(v[r]);
    }
  }
}

// ---------------- K5: parity scatter + separable FIR, one (b,o) per block --------------
// Row terms (kh,s) with u+s-1-kh even, h=(u+s-1-kh)/2 in [0,32): exactly 6 per u.
// Stage1: V[kw][u][w] = sum_rowterms F[s]*C[kh][kw][h][w]
// Stage2: out[u][v] = (1/16) * sum_colterms F[t]*V[kw][u][w], w=(v+t-1-kw)/2
__global__ __launch_bounds__(256) void k_fir(const ushort* __restrict__ C,
                                             float* __restrict__ out) {
  const int bo = blockIdx.x;
  const int b = bo >> 9, o = bo & 511;
  __shared__ __attribute__((aligned(16))) ushort Ct[9 * 1024];
  __shared__ float V[3 * 64 * 32];
  __shared__ int rb[64][6];
  __shared__ float rc[64][6];
  __shared__ int cb[64][6];
  __shared__ float cc[64][6];
  const ushort* Cb = C + ((size_t)(b * 9) * 512 + o) * 1024;  // + tap*512*1024
  for (int c = threadIdx.x; c < 1152; c += 256) {
    const int tap = c >> 7, off = (c & 127) * 8;
    *(uint4*)&Ct[tap * 1024 + off] = *(const uint4*)&Cb[(size_t)tap * 524288 + off];
  }
  const float F[4] = {1.f, 3.f, 3.f, 1.f};
  if (threadIdx.x < 64) {
    const int u = threadIdx.x;
    int n = 0;
    for (int kh = 0; kh < 3; kh++)
      for (int s = 0; s < 4; s++) {
        int num = u + s - 1 - kh;
        if (num & 1) continue;
        int h = num >> 1;
        bool val = (h >= 0 && h < 32);
        rb[u][n] = val ? kh * 3072 + h * 32 : 0;
        rc[u][n] = val ? F[s] : 0.f;
        n++;
      }
  } else if (threadIdx.x < 128) {
    const int v = threadIdx.x - 64;
    int n = 0;
    for (int kw = 0; kw < 3; kw++)
      for (int t = 0; t < 4; t++) {
        int num = v + t - 1 - kw;
        if (num & 1) continue;
        int w = num >> 1;
        bool val = (w >= 0 && w < 32);
        cb[v][n] = val ? kw * 2048 + w : 0;
        cc[v][n] = val ? F[t] : 0.f;
        n++;
      }
  }
  __syncthreads();
#pragma unroll
  for (int j = 0; j < 6; j++) {
    const int gidx = threadIdx.x + j * 256;  // 0..1535 : (kw, u, w0/4)
    const int kw = gidx >> 9;
    const int rem = gidx & 511;
    const int u = rem >> 3;
    const int w0 = (rem & 7) * 4;
    float a0 = 0.f, a1 = 0.f, a2 = 0.f, a3 = 0.f;
#pragma unroll
    for (int n = 0; n < 6; n++) {
      const float cf = rc[u][n];
      const ushort* p = &Ct[rb[u][n] + kw * 1024 + w0];
      a0 += cf * bf2f(p[0]);
      a1 += cf * bf2f(p[1]);
      a2 += cf * bf2f(p[2]);
      a3 += cf * bf2f(p[3]);
    }
    float4* vp = (float4*)&V[kw * 2048 + u * 32 + w0];
    *vp = make_float4(a0, a1, a2, a3);
  }
  __syncthreads();
  const size_t ob = (size_t)bo * 4096;
#pragma unroll
  for (int j = 0; j < 16; j++) {
    const int px = threadIdx.x + j * 256;
    const int u = px >> 6, v = px & 63;
    float s = 0.f;
#pragma unroll
    for (int n = 0; n < 6; n++) s += cc[v][n] * V[cb[v][n] + u * 32];
    out[ob + px] = s * 0.0625f;
  }
}

extern "C" void kernel_launch(void* const* d_in, const int* in_sizes, int n_in,
                              void* d_out, int out_size, void* d_ws, size_t ws_size,
                              hipStream_t stream) {
  (void)in_sizes; (void)n_in; (void)out_size; (void)ws_size;
  const float* x = (const float*)d_in[0];       // [8,512,32,32] fp32
  const float* styles = (const float*)d_in[1];  // [8,512] fp32
  const float* w = (const float*)d_in[2];       // [512,512,3,3] fp32
  float* out = (float*)d_out;                   // [8,512,64,64] fp32
  char* ws = (char*)d_ws;
  float* dcoef = (float*)ws;                                        // 16384 B
  ushort* Wm = (ushort*)(ws + 16384);                               // 37748736 B
  ushort* XT = (ushort*)(ws + 16384 + 37748736);                    // 8388608 B
  ushort* C = (ushort*)(ws + 16384 + 37748736 + 8388608);           // 75497472 B
  float* q = (float*)(ws + 16384 + 37748736 + 8388608 + 75497472);  // 1048576 B

  k_q<<<1024, 256, 0, stream>>>(w, q);
  k_dcoef<<<1024, 256, 0, stream>>>(q, styles, dcoef);
  k_wmprep<<<1024, 256, 0, stream>>>(w, styles, dcoef, Wm);
  k_xt<<<dim3(32, 16, 8), 256, 0, stream>>>(x, XT);
  k_gemm<<<2304, 256, 0, stream>>>(Wm, XT, C);
  k_fir<<<4096, 256, 0, stream>>>(C, out);
}

// Round 4
// 166.976 us; speedup vs baseline: 1.2119x; 1.0725x over previous
//
#include <hip/hip_runtime.h>
#include <stdint.h>

// ModulatedConv (StyleGAN2 up-conv): B=8, Cin=Cout=512, K=3, 32x32 -> 64x64, fp32 I/O.
// Pipeline (4 kernels):
//   K1 k_wprep: dcoef + Wm[b][tap][o][i] bf16 (37.75 MB) fused, block per o
//   K2 k_xt:    XT[b][hw][i] bf16 (8.39 MB), vectorized transpose
//   K3 k_gemm:  C[b*9+tap][o][hw] bf16 (75.5 MB), 72 GEMMs 512x1024x512,
//               MFMA 16x16x32, XCD-swizzled, LDS dbuf, LDS-staged coalesced epilogue
//   K4 k_fir:   parity scatter + separable 4x4 FIR per (b,o), closed-form taps

#define DI __device__ __forceinline__

typedef __bf16 bf16x8 __attribute__((ext_vector_type(8)));
typedef float f32x4 __attribute__((ext_vector_type(4)));

DI float bf2f(ushort u) { union { uint32_t i; float f; } v; v.i = ((uint32_t)u) << 16; return v.f; }
DI ushort f2bf(float f) {
  union { float f; uint32_t i; } v; v.f = f;
  uint32_t x = v.i;
  return (ushort)((x + 0x7FFFu + ((x >> 16) & 1u)) >> 16);  // RNE
}

#define GAIN (1.0f / 1536.0f)  // 1/sqrt(512*512*9)

// ---------------- K1: fused dcoef + Wm prep. Block per o (512 blocks). ------------------
// Thread t owns i = 2t, 2t+1; w[o][i][0..8] held in 18 VGPRs (contiguous 72 B/lane load).
__global__ __launch_bounds__(256) void k_wprep(const float* __restrict__ w,
                                               const float* __restrict__ styles,
                                               ushort* __restrict__ Wm) {
  const int o = blockIdx.x;
  const int t = threadIdx.x;
  __shared__ float ss[4096];  // styles[b][i]
  __shared__ float dc[8];
  __shared__ float wred[4][8];
#pragma unroll
  for (int j = 0; j < 4; j++) {
    const int idx = (t + j * 256) * 4;
    *(float4*)&ss[idx] = *(const float4*)&styles[idx];
  }
  float wreg[18];
  const float* wp = w + o * 4608 + t * 18;
#pragma unroll
  for (int k = 0; k < 9; k++) {
    float2 v2 = *(const float2*)(wp + 2 * k);
    wreg[2 * k] = v2.x;
    wreg[2 * k + 1] = v2.y;
  }
  float q0 = 0.f, q1 = 0.f;
#pragma unroll
  for (int k = 0; k < 9; k++) {
    q0 += wreg[k] * wreg[k];
    q1 += wreg[9 + k] * wreg[9 + k];
  }
  __syncthreads();  // ss ready
  float pb[8];
#pragma unroll
  for (int b = 0; b < 8; b++) {
    float s0 = ss[b * 512 + 2 * t] + 1.0f;
    float s1 = ss[b * 512 + 2 * t + 1] + 1.0f;
    pb[b] = s0 * s0 * q0 + s1 * s1 * q1;
  }
#pragma unroll
  for (int b = 0; b < 8; b++)
#pragma unroll
    for (int off = 32; off > 0; off >>= 1) pb[b] += __shfl_down(pb[b], off, 64);
  const int wid = t >> 6, lane = t & 63;
  if (lane == 0) {
#pragma unroll
    for (int b = 0; b < 8; b++) wred[wid][b] = pb[b];
  }
  __syncthreads();
  if (t < 8)
    dc[t] = rsqrtf((wred[0][t] + wred[1][t] + wred[2][t] + wred[3][t]) * (GAIN * GAIN) + 1e-8f);
  __syncthreads();
#pragma unroll
  for (int b = 0; b < 8; b++) {
    const float d = dc[b];
    const float s0 = GAIN * (ss[b * 512 + 2 * t] + 1.0f) * d;
    const float s1 = GAIN * (ss[b * 512 + 2 * t + 1] + 1.0f) * d;
    ushort* base = Wm + ((size_t)(b * 9) * 512 + o) * 512 + 2 * t;
#pragma unroll
    for (int tap = 0; tap < 9; tap++) {
      ushort2 val = make_ushort2(f2bf(wreg[tap] * s0), f2bf(wreg[9 + tap] * s1));
      *(ushort2*)(base + (size_t)tap * 262144) = val;
    }
  }
}

// ---------------- K2: XT[b][hw][i] = bf16(x[b][i][hw]), vectorized transpose ------------
// Tile 32 i x 256 hw. float4 loads, ushort4 stores. Grid (4 hw, 16 i, 8 b).
__global__ __launch_bounds__(256) void k_xt(const float* __restrict__ x,
                                            ushort* __restrict__ xt) {
  __shared__ float tl[32][257];
  const int b = blockIdx.z, i0 = blockIdx.y * 32, hw0 = blockIdx.x * 256;
  const int t = threadIdx.x;
  const float* xb = x + b * (512 * 1024);
#pragma unroll
  for (int p = 0; p < 8; p++) {
    const int r = p * 4 + (t >> 6);
    const int c4 = (t & 63) * 4;
    float4 v = *(const float4*)&xb[(i0 + r) * 1024 + hw0 + c4];
    tl[r][c4] = v.x; tl[r][c4 + 1] = v.y; tl[r][c4 + 2] = v.z; tl[r][c4 + 3] = v.w;
  }
  __syncthreads();
  ushort* xtb = xt + b * (1024 * 512);
#pragma unroll
  for (int p = 0; p < 8; p++) {
    const int hw = p * 32 + (t >> 3);
    const int i4 = (t & 7) * 4;
    ushort4 v = make_ushort4(f2bf(tl[i4][hw]), f2bf(tl[i4 + 1][hw]),
                             f2bf(tl[i4 + 2][hw]), f2bf(tl[i4 + 3][hw]));
    *(ushort4*)&xtb[(hw0 + hw) * 512 + i0 + i4] = v;
  }
}

// ---------------- K3: 72 x GEMM (M=512,N=1024,K=512), C = Wm @ X ------------------------
// A row-major [m=o][k=i], B^T row-major [n=hw][k=i]. 128x128 tile, BK=32, 4 waves.
// batch = id&7 (-> XCD), taps sequential per XCD -> B slab L2-resident.
// LDS double-buffered K-loop; epilogue staged through LDS for coalesced dwordx4 stores.
__global__ __launch_bounds__(256) void k_gemm(const ushort* __restrict__ A,
                                              const ushort* __restrict__ Bt,
                                              ushort* __restrict__ C) {
  __shared__ __attribute__((aligned(16))) char smem[32768];  // 2 x (A 8K | B 8K); reused as C-stage
  const int id = blockIdx.x;
  const int batch = id & 7;
  const int rem = id >> 3;
  const int tap = rem >> 5;
  const int t = rem & 31;
  const int mt = t >> 3, nt = t & 7;
  const int g = batch * 9 + tap;
  const ushort* Ag = A + g * (512 * 512);
  const ushort* Bg = Bt + batch * (1024 * 512);
  ushort* Cg = C + g * (512 * 1024);
  const int tid = threadIdx.x;
  const int lane = tid & 63, wv = tid >> 6;
  const int m0 = mt * 128, n0 = nt * 128;
  const int wm2 = wv >> 1, wn2 = wv & 1;
  const int lq = lane >> 4, l15 = lane & 15;
  const int l4 = lane & 3, ld4 = lane >> 2;
  const int r0 = (0 * 4 + wv) * 16 + ld4;
  const int r1 = (1 * 4 + wv) * 16 + ld4;

  const ushort* pA0 = Ag + (m0 + r0) * 512 + l4 * 8;
  const ushort* pA1 = Ag + (m0 + r1) * 512 + l4 * 8;
  const ushort* pB0 = Bg + (n0 + r0) * 512 + l4 * 8;
  const ushort* pB1 = Bg + (n0 + r1) * 512 + l4 * 8;
  char* dA0 = smem + (0 * 4 + wv) * 1024;
  char* dA1 = smem + (1 * 4 + wv) * 1024;
  char* dB0 = smem + 8192 + (0 * 4 + wv) * 1024;
  char* dB1 = smem + 8192 + (1 * 4 + wv) * 1024;

#define ISSUE(buf, kc)                                                                        \
  do {                                                                                        \
    __builtin_amdgcn_global_load_lds((const __attribute__((address_space(1))) void*)(pA0 + (kc)), \
                                     (__attribute__((address_space(3))) void*)(dA0 + (buf)*16384), 16, 0, 0); \
    __builtin_amdgcn_global_load_lds((const __attribute__((address_space(1))) void*)(pA1 + (kc)), \
                                     (__attribute__((address_space(3))) void*)(dA1 + (buf)*16384), 16, 0, 0); \
    __builtin_amdgcn_global_load_lds((const __attribute__((address_space(1))) void*)(pB0 + (kc)), \
                                     (__attribute__((address_space(3))) void*)(dB0 + (buf)*16384), 16, 0, 0); \
    __builtin_amdgcn_global_load_lds((const __attribute__((address_space(1))) void*)(pB1 + (kc)), \
                                     (__attribute__((address_space(3))) void*)(dB1 + (buf)*16384), 16, 0, 0); \
  } while (0)

  const char* abase = smem + (wm2 * 64 + l15) * 64 + lq * 16;
  const char* bbase = smem + 8192 + (wn2 * 64 + l15) * 64 + lq * 16;

  f32x4 zero = {0.f, 0.f, 0.f, 0.f};
  f32x4 acc[4][4];
#pragma unroll
  for (int mi = 0; mi < 4; mi++)
#pragma unroll
    for (int ni = 0; ni < 4; ni++) acc[mi][ni] = zero;

  ISSUE(0, 0);
  for (int it = 0; it < 16; ++it) {
    __syncthreads();
    const int cur = it & 1;
    if (it < 15) ISSUE(cur ^ 1, (it + 1) * 32);
    const int bo = cur * 16384;
    bf16x8 af[4], bfr[4];
#pragma unroll
    for (int mi = 0; mi < 4; mi++) af[mi] = *(const bf16x8*)(abase + bo + mi * 1024);
#pragma unroll
    for (int ni = 0; ni < 4; ni++) bfr[ni] = *(const bf16x8*)(bbase + bo + ni * 1024);
#pragma unroll
    for (int mi = 0; mi < 4; mi++)
#pragma unroll
      for (int ni = 0; ni < 4; ni++)
        acc[mi][ni] = __builtin_amdgcn_mfma_f32_16x16x32_bf16(af[mi], bfr[ni], acc[mi][ni], 0, 0, 0);
  }
#undef ISSUE
  // Epilogue: stage bf16 C tile in LDS, then coalesced 16B stores.
  __syncthreads();  // all waves' last ds_reads complete before smem reuse
  ushort* cs = (ushort*)smem;
#pragma unroll
  for (int mi = 0; mi < 4; mi++) {
#pragma unroll
    for (int ni = 0; ni < 4; ni++) {
      const int row = wm2 * 64 + mi * 16 + lq * 4;
      const int col = wn2 * 64 + ni * 16 + l15;
      f32x4 v = acc[mi][ni];
#pragma unroll
      for (int r = 0; r < 4; r++) cs[(row + r) * 128 + col] = f2bf(v[r]);
    }
  }
  __syncthreads();
#pragma unroll
  for (int p = 0; p < 8; p++) {
    const int r2 = p * 16 + (tid >> 4);
    const int c8 = (tid & 15) * 8;
    *(uint4*)(Cg + (m0 + r2) * 1024 + n0 + c8) = *(const uint4*)(cs + r2 * 128 + c8);
  }
}

// ---------------- K4: parity scatter + separable FIR, one (b,o) per block ---------------
// Row terms for output row u: kh in 0..2, s = s0+2d (s0=(kh+1+u)&1, d=0,1),
// h=(u+s-1-kh)/2 valid in [0,32); F[s] = (s0==d)?1:3. Same structure for columns.
// Stage1: V[kw][u][w] = sum F[s]*C[kh*3+kw][h][w]   (uint2 = 4 bf16 LDS loads)
// Stage2: out[u][v] = (1/16) sum F[t]*V[kw][u][(v+t-1-kw)/2]  (float4 stores)
__global__ __launch_bounds__(256) void k_fir(const ushort* __restrict__ C,
                                             float* __restrict__ out) {
  const int bo = blockIdx.x;
  const int b = bo >> 9, o = bo & 511;
  __shared__ __attribute__((aligned(16))) ushort Ct[9 * 1024];
  __shared__ float V[3 * 64 * 32];
  const ushort* Cb = C + ((size_t)(b * 9) * 512 + o) * 1024;
  for (int c = threadIdx.x; c < 1152; c += 256) {
    const int tap = c >> 7, off = (c & 127) * 8;
    *(uint4*)&Ct[tap * 1024 + off] = *(const uint4*)&Cb[(size_t)tap * 524288 + off];
  }
  __syncthreads();
#pragma unroll
  for (int j = 0; j < 6; j++) {
    const int gidx = threadIdx.x + j * 256;  // (kw, u, w0/4)
    const int kw = gidx >> 9;
    const int rem = gidx & 511;
    const int u = rem >> 3;
    const int w0 = (rem & 7) * 4;
    float a0 = 0.f, a1 = 0.f, a2 = 0.f, a3 = 0.f;
#pragma unroll
    for (int kh = 0; kh < 3; kh++) {
      const int s0 = (kh + 1 + u) & 1;
#pragma unroll
      for (int d = 0; d < 2; d++) {
        const int h = (u + s0 + 2 * d - 1 - kh) >> 1;
        const bool ok = (h >= 0) & (h < 32);
        const float cf = ok ? ((s0 == d) ? 1.f : 3.f) : 0.f;
        const int hh = ok ? h : 0;
        const uint2 cv = *(const uint2*)&Ct[kh * 3072 + kw * 1024 + hh * 32 + w0];
        a0 += cf * bf2f((ushort)(cv.x & 0xffff));
        a1 += cf * bf2f((ushort)(cv.x >> 16));
        a2 += cf * bf2f((ushort)(cv.y & 0xffff));
        a3 += cf * bf2f((ushort)(cv.y >> 16));
      }
    }
    *(float4*)&V[kw * 2048 + u * 32 + w0] = make_float4(a0, a1, a2, a3);
  }
  __syncthreads();
  const size_t ob = (size_t)bo * 4096;
#pragma unroll
  for (int p = 0; p < 4; p++) {
    const int u = p * 16 + (threadIdx.x >> 4);
    const int v0 = (threadIdx.x & 15) * 4;
    float r[4] = {0.f, 0.f, 0.f, 0.f};
#pragma unroll
    for (int q = 0; q < 4; q++) {
      const int v = v0 + q;
#pragma unroll
      for (int kw = 0; kw < 3; kw++) {
        const int t0 = (kw + 1 + v) & 1;
#pragma unroll
        for (int d = 0; d < 2; d++) {
          const int w = (v + t0 + 2 * d - 1 - kw) >> 1;
          const bool ok = (w >= 0) & (w < 32);
          const float cf = ok ? ((t0 == d) ? 1.f : 3.f) : 0.f;
          const int ww = ok ? w : 0;
          r[q] += cf * V[kw * 2048 + u * 32 + ww];
        }
      }
      r[q] *= 0.0625f;
    }
    *(float4*)&out[ob + u * 64 + v0] = make_float4(r[0], r[1], r[2], r[3]);
  }
}

extern "C" void kernel_launch(void* const* d_in, const int* in_sizes, int n_in,
                              void* d_out, int out_size, void* d_ws, size_t ws_size,
                              hipStream_t stream) {
  (void)in_sizes; (void)n_in; (void)out_size; (void)ws_size;
  const float* x = (const float*)d_in[0];       // [8,512,32,32] fp32
  const float* styles = (const float*)d_in[1];  // [8,512] fp32
  const float* w = (const float*)d_in[2];       // [512,512,3,3] fp32
  float* out = (float*)d_out;                   // [8,512,64,64] fp32
  char* ws = (char*)d_ws;
  ushort* Wm = (ushort*)ws;                        // 37748736 B
  ushort* XT = (ushort*)(ws + 37748736);           // 8388608 B
  ushort* C = (ushort*)(ws + 37748736 + 8388608);  // 75497472 B

  k_wprep<<<512, 256, 0, stream>>>(w, styles, Wm);
  k_xt<<<dim3(4, 16, 8), 256, 0, stream>>>(x, XT);
  k_gemm<<<2304, 256, 0, stream>>>(Wm, XT, C);
  k_fir<<<4096, 256, 0, stream>>>(C, out);
}

// Round 5
// 158.176 us; speedup vs baseline: 1.2793x; 1.0556x over previous
//
#include <hip/hip_runtime.h>
#include <stdint.h>

// ModulatedConv (StyleGAN2 up-conv): B=8, Cin=Cout=512, K=3, 32x32 -> 64x64, fp32 I/O.
// Pipeline (3 kernels):
//   K1 k_prep:  blocks 0..511  = dcoef + Wm[b][tap][o][i] bf16 (37.75 MB), block per o
//               blocks 512..1023 = XT[b][hw][i] bf16 (8.39 MB) transpose
//   K2 k_gemm:  C[b*9+tap][o][hw] bf16 (75.5 MB), 72 GEMMs 512x1024x512,
//               MFMA 16x16x32, XCD-swizzled, LDS dbuf, padded LDS-staged epilogue
//   K3 k_fir:   parity scatter + separable 4x4 FIR per (b,o), 512 thr, padded V

#define DI __device__ __forceinline__

typedef __bf16 bf16x8 __attribute__((ext_vector_type(8)));
typedef float f32x4 __attribute__((ext_vector_type(4)));

DI float bf2f(ushort u) { union { uint32_t i; float f; } v; v.i = ((uint32_t)u) << 16; return v.f; }
DI ushort f2bf(float f) {
  union { float f; uint32_t i; } v; v.f = f;
  uint32_t x = v.i;
  return (ushort)((x + 0x7FFFu + ((x >> 16) & 1u)) >> 16);  // RNE
}

#define GAIN (1.0f / 1536.0f)  // 1/sqrt(512*512*9)

// ---------------- K1: fused weight-prep (blocks 0..511) + x-transpose (512..1023) -------
__global__ __launch_bounds__(256) void k_prep(const float* __restrict__ w,
                                              const float* __restrict__ styles,
                                              const float* __restrict__ x,
                                              ushort* __restrict__ Wm,
                                              ushort* __restrict__ xt) {
  __shared__ union {
    struct { float ss[4096]; float dc[8]; float wred[4][8]; } wp;
    float tl[32][257];
  } sm;
  const int t = threadIdx.x;
  if (blockIdx.x < 512) {
    // ---- weight prep: block per o. Thread t owns i = 2t, 2t+1. ----
    const int o = blockIdx.x;
#pragma unroll
    for (int j = 0; j < 4; j++) {
      const int idx = (t + j * 256) * 4;
      *(float4*)&sm.wp.ss[idx] = *(const float4*)&styles[idx];
    }
    float wreg[18];
    const float* wp_ = w + o * 4608 + t * 18;
#pragma unroll
    for (int k = 0; k < 9; k++) {
      float2 v2 = *(const float2*)(wp_ + 2 * k);
      wreg[2 * k] = v2.x;
      wreg[2 * k + 1] = v2.y;
    }
    float q0 = 0.f, q1 = 0.f;
#pragma unroll
    for (int k = 0; k < 9; k++) {
      q0 += wreg[k] * wreg[k];
      q1 += wreg[9 + k] * wreg[9 + k];
    }
    __syncthreads();  // ss ready
    float pb[8];
#pragma unroll
    for (int b = 0; b < 8; b++) {
      float s0 = sm.wp.ss[b * 512 + 2 * t] + 1.0f;
      float s1 = sm.wp.ss[b * 512 + 2 * t + 1] + 1.0f;
      pb[b] = s0 * s0 * q0 + s1 * s1 * q1;
    }
#pragma unroll
    for (int b = 0; b < 8; b++)
#pragma unroll
      for (int off = 32; off > 0; off >>= 1) pb[b] += __shfl_down(pb[b], off, 64);
    const int wid = t >> 6, lane = t & 63;
    if (lane == 0) {
#pragma unroll
      for (int b = 0; b < 8; b++) sm.wp.wred[wid][b] = pb[b];
    }
    __syncthreads();
    if (t < 8)
      sm.wp.dc[t] = rsqrtf((sm.wp.wred[0][t] + sm.wp.wred[1][t] + sm.wp.wred[2][t] + sm.wp.wred[3][t]) *
                               (GAIN * GAIN) + 1e-8f);
    __syncthreads();
#pragma unroll
    for (int b = 0; b < 8; b++) {
      const float d = sm.wp.dc[b];
      const float s0 = GAIN * (sm.wp.ss[b * 512 + 2 * t] + 1.0f) * d;
      const float s1 = GAIN * (sm.wp.ss[b * 512 + 2 * t + 1] + 1.0f) * d;
      ushort* base = Wm + ((size_t)(b * 9) * 512 + o) * 512 + 2 * t;
#pragma unroll
      for (int tap = 0; tap < 9; tap++) {
        ushort2 val = make_ushort2(f2bf(wreg[tap] * s0), f2bf(wreg[9 + tap] * s1));
        *(ushort2*)(base + (size_t)tap * 262144) = val;
      }
    }
  } else {
    // ---- x transpose: tile 32 i x 256 hw ----
    const int idx = blockIdx.x - 512;
    const int hw0 = (idx & 3) * 256, i0 = ((idx >> 2) & 15) * 32, b = idx >> 6;
    const float* xb = x + b * (512 * 1024);
#pragma unroll
    for (int p = 0; p < 8; p++) {
      const int r = p * 4 + (t >> 6);
      const int c4 = (t & 63) * 4;
      float4 v = *(const float4*)&xb[(i0 + r) * 1024 + hw0 + c4];
      sm.tl[r][c4] = v.x; sm.tl[r][c4 + 1] = v.y; sm.tl[r][c4 + 2] = v.z; sm.tl[r][c4 + 3] = v.w;
    }
    __syncthreads();
    ushort* xtb = xt + b * (1024 * 512);
#pragma unroll
    for (int p = 0; p < 8; p++) {
      const int hw = p * 32 + (t >> 3);
      const int i4 = (t & 7) * 4;
      ushort4 v = make_ushort4(f2bf(sm.tl[i4][hw]), f2bf(sm.tl[i4 + 1][hw]),
                               f2bf(sm.tl[i4 + 2][hw]), f2bf(sm.tl[i4 + 3][hw]));
      *(ushort4*)&xtb[(hw0 + hw) * 512 + i0 + i4] = v;
    }
  }
}

// ---------------- K2: 72 x GEMM (M=512,N=1024,K=512), C = Wm @ X ------------------------
// A row-major [m=o][k=i], B^T row-major [n=hw][k=i]. 128x128 tile, BK=32, 4 waves.
// batch = id&7 (-> XCD), taps sequential per XCD -> B slab L2-resident.
// LDS dbuf K-loop; epilogue staged through LDS (row stride 136 = 16-bank spread).
__global__ __launch_bounds__(256) void k_gemm(const ushort* __restrict__ A,
                                              const ushort* __restrict__ Bt,
                                              ushort* __restrict__ C) {
  __shared__ __attribute__((aligned(16))) char smem[34816];  // 2x(A 8K|B 8K); C-stage 128x136x2
  const int id = blockIdx.x;
  const int batch = id & 7;
  const int rem = id >> 3;
  const int tap = rem >> 5;
  const int t = rem & 31;
  const int mt = t >> 3, nt = t & 7;
  const int g = batch * 9 + tap;
  const ushort* Ag = A + g * (512 * 512);
  const ushort* Bg = Bt + batch * (1024 * 512);
  ushort* Cg = C + g * (512 * 1024);
  const int tid = threadIdx.x;
  const int lane = tid & 63, wv = tid >> 6;
  const int m0 = mt * 128, n0 = nt * 128;
  const int wm2 = wv >> 1, wn2 = wv & 1;
  const int lq = lane >> 4, l15 = lane & 15;
  const int l4 = lane & 3, ld4 = lane >> 2;
  const int r0 = (0 * 4 + wv) * 16 + ld4;
  const int r1 = (1 * 4 + wv) * 16 + ld4;

  const ushort* pA0 = Ag + (m0 + r0) * 512 + l4 * 8;
  const ushort* pA1 = Ag + (m0 + r1) * 512 + l4 * 8;
  const ushort* pB0 = Bg + (n0 + r0) * 512 + l4 * 8;
  const ushort* pB1 = Bg + (n0 + r1) * 512 + l4 * 8;
  char* dA0 = smem + (0 * 4 + wv) * 1024;
  char* dA1 = smem + (1 * 4 + wv) * 1024;
  char* dB0 = smem + 8192 + (0 * 4 + wv) * 1024;
  char* dB1 = smem + 8192 + (1 * 4 + wv) * 1024;

#define ISSUE(buf, kc)                                                                        \
  do {                                                                                        \
    __builtin_amdgcn_global_load_lds((const __attribute__((address_space(1))) void*)(pA0 + (kc)), \
                                     (__attribute__((address_space(3))) void*)(dA0 + (buf)*16384), 16, 0, 0); \
    __builtin_amdgcn_global_load_lds((const __attribute__((address_space(1))) void*)(pA1 + (kc)), \
                                     (__attribute__((address_space(3))) void*)(dA1 + (buf)*16384), 16, 0, 0); \
    __builtin_amdgcn_global_load_lds((const __attribute__((address_space(1))) void*)(pB0 + (kc)), \
                                     (__attribute__((address_space(3))) void*)(dB0 + (buf)*16384), 16, 0, 0); \
    __builtin_amdgcn_global_load_lds((const __attribute__((address_space(1))) void*)(pB1 + (kc)), \
                                     (__attribute__((address_space(3))) void*)(dB1 + (buf)*16384), 16, 0, 0); \
  } while (0)

  const char* abase = smem + (wm2 * 64 + l15) * 64 + lq * 16;
  const char* bbase = smem + 8192 + (wn2 * 64 + l15) * 64 + lq * 16;

  f32x4 zero = {0.f, 0.f, 0.f, 0.f};
  f32x4 acc[4][4];
#pragma unroll
  for (int mi = 0; mi < 4; mi++)
#pragma unroll
    for (int ni = 0; ni < 4; ni++) acc[mi][ni] = zero;

  ISSUE(0, 0);
  for (int it = 0; it < 16; ++it) {
    __syncthreads();
    const int cur = it & 1;
    if (it < 15) ISSUE(cur ^ 1, (it + 1) * 32);
    const int bo = cur * 16384;
    bf16x8 af[4], bfr[4];
#pragma unroll
    for (int mi = 0; mi < 4; mi++) af[mi] = *(const bf16x8*)(abase + bo + mi * 1024);
#pragma unroll
    for (int ni = 0; ni < 4; ni++) bfr[ni] = *(const bf16x8*)(bbase + bo + ni * 1024);
#pragma unroll
    for (int mi = 0; mi < 4; mi++)
#pragma unroll
      for (int ni = 0; ni < 4; ni++)
        acc[mi][ni] = __builtin_amdgcn_mfma_f32_16x16x32_bf16(af[mi], bfr[ni], acc[mi][ni], 0, 0, 0);
  }
#undef ISSUE
  // Epilogue: stage bf16 C tile in LDS (stride 136), then coalesced 16B stores.
  __syncthreads();
  ushort* cs = (ushort*)smem;
#pragma unroll
  for (int mi = 0; mi < 4; mi++) {
#pragma unroll
    for (int ni = 0; ni < 4; ni++) {
      const int row = wm2 * 64 + mi * 16 + lq * 4;
      const int col = wn2 * 64 + ni * 16 + l15;
      f32x4 v = acc[mi][ni];
#pragma unroll
      for (int r = 0; r < 4; r++) cs[(row + r) * 136 + col] = f2bf(v[r]);
    }
  }
  __syncthreads();
#pragma unroll
  for (int p = 0; p < 8; p++) {
    const int r2 = p * 16 + (tid >> 4);
    const int c8 = (tid & 15) * 8;
    *(uint4*)(Cg + (m0 + r2) * 1024 + n0 + c8) = *(const uint4*)(cs + r2 * 136 + c8);
  }
}

// ---------------- K3: parity scatter + separable FIR, one (b,o) per block, 512 thr ------
// Stage1: V[kw][u][w] = sum_{kh,d} F*C[kh*3+kw][h][w], V row stride 36 (bank spread)
// Stage2: out[u][v] = (1/16) sum_{kw,d} F*V[kw][u][(v+t0+2d-1-kw)/2]
__global__ __launch_bounds__(512) void k_fir(const ushort* __restrict__ C,
                                             float* __restrict__ out) {
  const int bo = blockIdx.x;
  const int b = bo >> 9, o = bo & 511;
  __shared__ __attribute__((aligned(16))) ushort Ct[9 * 1024];
  __shared__ float V[3 * 64 * 36];
  const ushort* Cb = C + ((size_t)(b * 9) * 512 + o) * 1024;
  for (int c = threadIdx.x; c < 1152; c += 512) {
    const int tap = c >> 7, off = (c & 127) * 8;
    *(uint4*)&Ct[tap * 1024 + off] = *(const uint4*)&Cb[(size_t)tap * 524288 + off];
  }
  __syncthreads();
#pragma unroll
  for (int j = 0; j < 3; j++) {
    const int gidx = threadIdx.x + j * 512;  // (kw, u, w0/4)
    const int kw = gidx >> 9;
    const int rem = gidx & 511;
    const int u = rem >> 3;
    const int w0 = (rem & 7) * 4;
    float a0 = 0.f, a1 = 0.f, a2 = 0.f, a3 = 0.f;
#pragma unroll
    for (int kh = 0; kh < 3; kh++) {
      const int s0 = (kh + 1 + u) & 1;
#pragma unroll
      for (int d = 0; d < 2; d++) {
        const int h = (u + s0 + 2 * d - 1 - kh) >> 1;
        const bool ok = (h >= 0) & (h < 32);
        const float cf = ok ? ((s0 == d) ? 1.f : 3.f) : 0.f;
        const int hh = ok ? h : 0;
        const uint2 cv = *(const uint2*)&Ct[kh * 3072 + kw * 1024 + hh * 32 + w0];
        a0 += cf * bf2f((ushort)(cv.x & 0xffff));
        a1 += cf * bf2f((ushort)(cv.x >> 16));
        a2 += cf * bf2f((ushort)(cv.y & 0xffff));
        a3 += cf * bf2f((ushort)(cv.y >> 16));
      }
    }
    *(float4*)&V[kw * 2304 + u * 36 + w0] = make_float4(a0, a1, a2, a3);
  }
  __syncthreads();
  const size_t ob = (size_t)bo * 4096;
#pragma unroll
  for (int j = 0; j < 2; j++) {
    const int px4 = threadIdx.x + j * 512;
    const int u = px4 >> 4;
    const int v0 = (px4 & 15) * 4;
    float r[4] = {0.f, 0.f, 0.f, 0.f};
#pragma unroll
    for (int q = 0; q < 4; q++) {
      const int v = v0 + q;
#pragma unroll
      for (int kw = 0; kw < 3; kw++) {
        const int t0 = (kw + 1 + v) & 1;
#pragma unroll
        for (int d = 0; d < 2; d++) {
          const int wx = (v + t0 + 2 * d - 1 - kw) >> 1;
          const bool ok = (wx >= 0) & (wx < 32);
          const float cf = ok ? ((t0 == d) ? 1.f : 3.f) : 0.f;
          const int ww = ok ? wx : 0;
          r[q] += cf * V[kw * 2304 + u * 36 + ww];
        }
      }
      r[q] *= 0.0625f;
    }
    *(float4*)&out[ob + u * 64 + v0] = make_float4(r[0], r[1], r[2], r[3]);
  }
}

extern "C" void kernel_launch(void* const* d_in, const int* in_sizes, int n_in,
                              void* d_out, int out_size, void* d_ws, size_t ws_size,
                              hipStream_t stream) {
  (void)in_sizes; (void)n_in; (void)out_size; (void)ws_size;
  const float* x = (const float*)d_in[0];       // [8,512,32,32] fp32
  const float* styles = (const float*)d_in[1];  // [8,512] fp32
  const float* w = (const float*)d_in[2];       // [512,512,3,3] fp32
  float* out = (float*)d_out;                   // [8,512,64,64] fp32
  char* ws = (char*)d_ws;
  ushort* Wm = (ushort*)ws;                        // 37748736 B
  ushort* XT = (ushort*)(ws + 37748736);           // 8388608 B
  ushort* C = (ushort*)(ws + 37748736 + 8388608);  // 75497472 B

  k_prep<<<1024, 256, 0, stream>>>(w, styles, x, Wm, XT);
  k_gemm<<<2304, 256, 0, stream>>>(Wm, XT, C);
  k_fir<<<4096, 512, 0, stream>>>(C, out);
}